// Round 1
// baseline (507.720 us; speedup 1.0000x reference)
//
#include <hip/hip_runtime.h>

// DualMemoryBlock: rmsnorm -> {windowed attn, oscillator TRN} -> gated mix -> SwiGLU FFN
// All big matmuls: bf16 MFMA 16x16x32, 128x128 tile, BK=32, global_load_lds(16B) staging.

typedef unsigned short u16;
typedef unsigned short u16x8 __attribute__((ext_vector_type(8)));
typedef __bf16 bf16x8 __attribute__((ext_vector_type(8)));
typedef float f32x4 __attribute__((ext_vector_type(4)));

#define DI static __device__ __forceinline__

DI u16 f2b(float f){
  union { float f; unsigned u; } v; v.f = f;
  unsigned r = v.u + 0x7FFFu + ((v.u >> 16) & 1u);
  return (u16)(r >> 16);
}
DI float b2f(u16 b){
  union { unsigned u; float f; } v; v.u = ((unsigned)b) << 16; return v.f;
}
DI u16x8 ld8(const u16* p){ return *(const u16x8*)p; }

DI f32x4 MFMA16(u16x8 a, u16x8 b, f32x4 c){
  return __builtin_amdgcn_mfma_f32_16x16x32_bf16(
      __builtin_bit_cast(bf16x8, a), __builtin_bit_cast(bf16x8, b), c, 0, 0, 0);
}

DI void async16(const void* g, void* l){
  void* gg = const_cast<void*>(g);
  __builtin_amdgcn_global_load_lds(
      (__attribute__((address_space(1))) void*)gg,
      (__attribute__((address_space(3))) void*)l, 16, 0, 0);
}

// ---------------------------------------------------------------------------
// Weight conversion fp32 -> bf16 into one packed buffer.
// sections (elements): qkv 3145728 | proj 1048576 | ffn_gate 4194304 |
//  ffn_up 4194304 | ffn_down 4194304 | trn combined(128x1024, rows64+ = 0) 131072 |
//  wout 32768   => total 17041408
// ---------------------------------------------------------------------------
__global__ __launch_bounds__(256) void convert_w(
    const float* __restrict__ qkvw, const float* __restrict__ projw,
    const float* __restrict__ fgw, const float* __restrict__ fuw,
    const float* __restrict__ fdw, const float* __restrict__ twin,
    const float* __restrict__ tgw, const float* __restrict__ twout,
    u16* __restrict__ dst)
{
  size_t i = (size_t)blockIdx.x * 256 + threadIdx.x;
  if (i >= 4260352u) return;
  size_t e = i * 4;
  float4 v;
  if (e < 3145728u)        v = *(const float4*)(qkvw + e);
  else if (e < 4194304u)   v = *(const float4*)(projw + (e - 3145728u));
  else if (e < 8388608u)   v = *(const float4*)(fgw + (e - 4194304u));
  else if (e < 12582912u)  v = *(const float4*)(fuw + (e - 8388608u));
  else if (e < 16777216u)  v = *(const float4*)(fdw + (e - 12582912u));
  else if (e < 16908288u){
    size_t i2 = e - 16777216u;
    int row = (int)(i2 >> 10), c = (int)(i2 & 1023);
    if (row < 32)      v = *(const float4*)(twin + row * 1024 + c);
    else if (row < 64) v = *(const float4*)(tgw + (row - 32) * 1024 + c);
    else               v = make_float4(0.f, 0.f, 0.f, 0.f);
  } else {
    v = *(const float4*)(twout + (e - 16908288u));
  }
  uint2 p;
  p.x = (unsigned)f2b(v.x) | ((unsigned)f2b(v.y) << 16);
  p.y = (unsigned)f2b(v.z) | ((unsigned)f2b(v.w) << 16);
  *(uint2*)(dst + e) = p;
}

// ---------------------------------------------------------------------------
// RMSNorm (+ fused scalar gate logit for norm1)
// ---------------------------------------------------------------------------
__global__ __launch_bounds__(256) void rmsnorm_gate(
    const float* __restrict__ x, const float* __restrict__ w,
    const float* __restrict__ gw, const float* __restrict__ gb,
    u16* __restrict__ h, float* __restrict__ g)
{
  const int row = blockIdx.x, tid = threadIdx.x;
  const int wave = tid >> 6, lane = tid & 63;
  __shared__ float sb[8];
  float4 xv = ((const float4*)(x + (size_t)row * 1024))[tid];
  float ss = xv.x*xv.x + xv.y*xv.y + xv.z*xv.z + xv.w*xv.w;
#pragma unroll
  for (int m = 32; m; m >>= 1) ss += __shfl_xor(ss, m);
  if (lane == 0) sb[wave] = ss;
  __syncthreads();
  float rstd = rsqrtf((sb[0]+sb[1]+sb[2]+sb[3]) * (1.f/1024.f) + 1e-6f);
  float4 wv = ((const float4*)w)[tid];
  float h0 = xv.x*rstd*wv.x, h1 = xv.y*rstd*wv.y;
  float h2v = xv.z*rstd*wv.z, h3 = xv.w*rstd*wv.w;
  uint2 pk;
  pk.x = (unsigned)f2b(h0) | ((unsigned)f2b(h1) << 16);
  pk.y = (unsigned)f2b(h2v) | ((unsigned)f2b(h3) << 16);
  ((uint2*)(h + (size_t)row * 1024))[tid] = pk;
  float4 gv = ((const float4*)gw)[tid];
  float gd = h0*gv.x + h1*gv.y + h2v*gv.z + h3*gv.w;
#pragma unroll
  for (int m = 32; m; m >>= 1) gd += __shfl_xor(gd, m);
  if (lane == 0) sb[4 + wave] = gd;
  __syncthreads();
  if (tid == 0) g[row] = 1.f / (1.f + __expf(-(sb[4]+sb[5]+sb[6]+sb[7] + gb[0])));
}

__global__ __launch_bounds__(256) void rmsnorm_plain(
    const float* __restrict__ x, const float* __restrict__ w, u16* __restrict__ h)
{
  const int row = blockIdx.x, tid = threadIdx.x;
  const int wave = tid >> 6, lane = tid & 63;
  __shared__ float sb[4];
  float4 xv = ((const float4*)(x + (size_t)row * 1024))[tid];
  float ss = xv.x*xv.x + xv.y*xv.y + xv.z*xv.z + xv.w*xv.w;
#pragma unroll
  for (int m = 32; m; m >>= 1) ss += __shfl_xor(ss, m);
  if (lane == 0) sb[wave] = ss;
  __syncthreads();
  float rstd = rsqrtf((sb[0]+sb[1]+sb[2]+sb[3]) * (1.f/1024.f) + 1e-6f);
  float4 wv = ((const float4*)w)[tid];
  uint2 pk;
  pk.x = (unsigned)f2b(xv.x*rstd*wv.x) | ((unsigned)f2b(xv.y*rstd*wv.y) << 16);
  pk.y = (unsigned)f2b(xv.z*rstd*wv.z) | ((unsigned)f2b(xv.w*rstd*wv.w) << 16);
  ((uint2*)(h + (size_t)row * 1024))[tid] = pk;
}

// ---------------------------------------------------------------------------
// GEMM: out[m,n] = sum_k A[m,k]*B[n,k]  (both row-major bf16, fp32 accum)
// 128x128 tile, BK=32, 256 threads = 2x2 waves, each wave 64x64 (4x4 MFMAs).
// MODE epilogues:
//  0: outB = bf16(v + bias[col])                         (qkv)
//  1: outB = bf16(silu(v))                               (ffn gate)
//  2: outB = bf16(v * b2f(aux16[idx]))                   (ffn up * silu(gate))
//  3: outF = auxF[idx] + v                               (ffn down + residual)
//  4: outF = auxF + g*(v+bias) + (1-g)*trn               (proj + gated mix)
//  5: col<32 -> u_t[b,k,t]=v ; col<64 -> tg=sigmoid(v+b) (trn drive + gate)
//  6: outB = bf16(v * auxF[0])                           (trn_out, res_scale)
// ---------------------------------------------------------------------------
template<int MODE>
__global__ __launch_bounds__(256) void gemm_bt(
    const u16* __restrict__ A, const u16* __restrict__ B,
    float* __restrict__ outF, float* __restrict__ outF2, u16* __restrict__ outB,
    const float* __restrict__ bias, const u16* __restrict__ aux16,
    const float* __restrict__ auxF, const float* __restrict__ auxG,
    int M, int N, int K)
{
  (void)M;
  __shared__ __align__(16) u16 sA[128 * 32];
  __shared__ __align__(16) u16 sB[128 * 32];
  const int tid = threadIdx.x;
  const int wave = tid >> 6, lane = tid & 63;
  const int lr = lane & 15, lq = lane >> 4;
  const int m0 = blockIdx.x * 128, n0 = blockIdx.y * 128;
  const int wm = (wave & 1) * 64, wn = (wave >> 1) * 64;
  f32x4 acc[4][4] = {};
  const int srow = wave * 16 + (lane >> 2);
  const int scol = (lane & 3) * 8;
  const u16* gA = A + (size_t)(m0 + srow) * K + scol;
  const u16* gB = B + (size_t)(n0 + srow) * K + scol;
  u16* lA0 = &sA[(wave * 16) * 32];
  u16* lA1 = &sA[(64 + wave * 16) * 32];
  u16* lB0 = &sB[(wave * 16) * 32];
  u16* lB1 = &sB[(64 + wave * 16) * 32];
  const size_t K64 = (size_t)64 * K;

  for (int k0 = 0; k0 < K; k0 += 32){
    async16(gA + k0,       lA0);
    async16(gA + K64 + k0, lA1);
    async16(gB + k0,       lB0);
    async16(gB + K64 + k0, lB1);
    __syncthreads();
    u16x8 af[4], bf[4];
#pragma unroll
    for (int i = 0; i < 4; i++) af[i] = ld8(&sA[(wm + i*16 + lr)*32 + lq*8]);
#pragma unroll
    for (int i = 0; i < 4; i++) bf[i] = ld8(&sB[(wn + i*16 + lr)*32 + lq*8]);
#pragma unroll
    for (int mi = 0; mi < 4; mi++)
#pragma unroll
      for (int ni = 0; ni < 4; ni++)
        acc[mi][ni] = MFMA16(af[mi], bf[ni], acc[mi][ni]);
    __syncthreads();
  }

  float scale6 = 0.f;
  if (MODE == 6) scale6 = auxF[0];

#pragma unroll
  for (int mi = 0; mi < 4; mi++){
    const int row = m0 + wm + mi*16 + lq*4;
#pragma unroll
    for (int ni = 0; ni < 4; ni++){
      const int col = n0 + wn + ni*16 + lr;
#pragma unroll
      for (int r = 0; r < 4; r++){
        const int rr = row + r;
        const size_t idx = (size_t)rr * N + col;
        float v = acc[mi][ni][r];
        if (MODE == 0){ outB[idx] = f2b(v + bias[col]); }
        else if (MODE == 1){ outB[idx] = f2b(v / (1.f + __expf(-v))); }
        else if (MODE == 2){ outB[idx] = f2b(v * b2f(aux16[idx])); }
        else if (MODE == 3){ outF[idx] = auxF[idx] + v; }
        else if (MODE == 4){
          float gg = auxG[rr];
          outF[idx] = auxF[idx] + gg * (v + bias[col]) + (1.f - gg) * b2f(aux16[idx]);
        }
        else if (MODE == 5){
          int bb = rr >> 11, tt = rr & 2047;
          if (col < 32) outF[((size_t)bb * 32 + col) * 2048 + tt] = v;
          else if (col < 64)
            outF2[(size_t)rr * 32 + (col - 32)] =
                1.f / (1.f + __expf(-(v + bias[col - 32])));
        }
        else if (MODE == 6){ outB[idx] = f2b(v * scale6); }
      }
    }
  }
}

// ---------------------------------------------------------------------------
// Windowed causal flash attention. qkv: [B*T, 3072] bf16 (q|k|v, 16 heads x 64).
// Block = (b,h,64-query tile); wave w owns 16 queries. 32-key tiles, masked.
// ---------------------------------------------------------------------------
__global__ __launch_bounds__(256) void attn_win(
    const u16* __restrict__ qkv, u16* __restrict__ ao)
{
  const int blk = blockIdx.x;
  const int tile = blk & 31, hh = (blk >> 5) & 15, b = blk >> 9;
  const int t0 = tile * 64;
  const int tid = threadIdx.x, wave = tid >> 6, lane = tid & 63;
  const int lr = lane & 15, lq = lane >> 4;
  const int qt = t0 + wave * 16;
  __shared__ __align__(16) u16 sVt[64 * 40];      // V^T, padded stride 40
  __shared__ __align__(16) u16 sP[4][16 * 32];    // per-wave P buffer

  const u16* base = qkv + (size_t)b * 2048 * 3072 + hh * 64;
  const u16* qrow = base + (size_t)(qt + lr) * 3072 + lq * 8;
  u16x8 qf0 = ld8(qrow), qf1 = ld8(qrow + 32);
  const u16* kbase = base + 1024;
  const u16* vbase = base + 2048;

  f32x4 o0 = {0,0,0,0}, o1 = {0,0,0,0}, o2 = {0,0,0,0}, o3 = {0,0,0,0};
  float mrun[4] = {-1e30f, -1e30f, -1e30f, -1e30f};
  float lrun[4] = {0.f, 0.f, 0.f, 0.f};
  const float c1 = 0.125f * 1.44269504088896f;  // scale * log2(e)

  const int kb = (t0 >= 256) ? (t0 - 256) : 0;
  const int ntl = (t0 + 64 - kb) >> 5;
  for (int it = 0; it < ntl; ++it){
    const int kt = kb + it * 32;
    __syncthreads();                 // prev-iter LDS reads done
    if (tid < 128){                  // stage V^T (32 keys x 64 dims)
      const int key = tid & 31, dh = tid >> 5;
      const u16* gv = vbase + (size_t)(kt + key) * 3072 + dh * 16;
      u16x8 v0 = ld8(gv), v1 = ld8(gv + 8);
#pragma unroll
      for (int j = 0; j < 8; j++){
        sVt[(dh*16 + j)     * 40 + key] = v0[j];
        sVt[(dh*16 + 8 + j) * 40 + key] = v1[j];
      }
    }
    __syncthreads();
    const bool active = (kt < qt + 16) && (kt + 286 >= qt);
    if (!active) continue;           // both barriers are above: counts stay equal

    f32x4 s0 = {0,0,0,0}, s1 = {0,0,0,0};
    {
      const u16* kr = kbase + (size_t)(kt + lr) * 3072 + lq * 8;
      u16x8 k00 = ld8(kr), k01 = ld8(kr + 32);
      const u16* kr1 = kr + (size_t)16 * 3072;
      u16x8 k10 = ld8(kr1), k11 = ld8(kr1 + 32);
      s0 = MFMA16(qf0, k00, s0); s0 = MFMA16(qf1, k01, s0);
      s1 = MFMA16(qf0, k10, s1); s1 = MFMA16(qf1, k11, s1);
    }
    float al[4];
#pragma unroll
    for (int r = 0; r < 4; r++){
      const int q = qt + lq * 4 + r;
      const int ca = kt + lr, cb = kt + 16 + lr;
      float a0 = (ca <= q && ca + 255 >= q) ? s0[r] : -1e30f;
      float a1 = (cb <= q && cb + 255 >= q) ? s1[r] : -1e30f;
      float mx = fmaxf(a0, a1);
      mx = fmaxf(mx, __shfl_xor(mx, 1));
      mx = fmaxf(mx, __shfl_xor(mx, 2));
      mx = fmaxf(mx, __shfl_xor(mx, 4));
      mx = fmaxf(mx, __shfl_xor(mx, 8));
      float mn = fmaxf(mrun[r], mx);
      al[r] = exp2f((mrun[r] - mn) * c1);
      mrun[r] = mn;
      float p0 = (a0 > -1e29f) ? exp2f((a0 - mn) * c1) : 0.f;
      float p1 = (a1 > -1e29f) ? exp2f((a1 - mn) * c1) : 0.f;
      float sm = p0 + p1;
      sm += __shfl_xor(sm, 1); sm += __shfl_xor(sm, 2);
      sm += __shfl_xor(sm, 4); sm += __shfl_xor(sm, 8);
      lrun[r] = lrun[r] * al[r] + sm;
      sP[wave][(lq*4 + r) * 32 + lr]      = f2b(p0);
      sP[wave][(lq*4 + r) * 32 + 16 + lr] = f2b(p1);
    }
#pragma unroll
    for (int r = 0; r < 4; r++){
      o0[r] *= al[r]; o1[r] *= al[r]; o2[r] *= al[r]; o3[r] *= al[r];
    }
    __builtin_amdgcn_s_waitcnt(0xc07f);   // lgkmcnt(0): P writes visible
    u16x8 pf = ld8(&sP[wave][lr * 32 + lq * 8]);
    o0 = MFMA16(pf, ld8(&sVt[(lr)      * 40 + lq * 8]), o0);
    o1 = MFMA16(pf, ld8(&sVt[(16 + lr) * 40 + lq * 8]), o1);
    o2 = MFMA16(pf, ld8(&sVt[(32 + lr) * 40 + lq * 8]), o2);
    o3 = MFMA16(pf, ld8(&sVt[(48 + lr) * 40 + lq * 8]), o3);
  }

  u16* aor = ao + (size_t)(b * 2048 + qt + lq * 4) * 1024 + hh * 64 + lr;
#pragma unroll
  for (int r = 0; r < 4; r++){
    float inv = 1.f / lrun[r];
    u16* p = aor + (size_t)r * 1024;
    p[0]  = f2b(o0[r] * inv);
    p[16] = f2b(o1[r] * inv);
    p[32] = f2b(o2[r] * inv);
    p[48] = f2b(o3[r] * inv);
  }
}

// ---------------------------------------------------------------------------
// Oscillator scan: s_t = w*s_{t-1} + u_t (complex w = a e^{i theta}), y=Re(s).
// One block per (b,k); 256 threads x 8-step segments; Hillis-Steele over
// affine maps (A,b): z -> A z + b, composed with complex multiplies.
// Writes z[b,t,k] = y * tg (bf16).
// ---------------------------------------------------------------------------
__global__ __launch_bounds__(256) void scan_k(
    const float* __restrict__ u_t, const float* __restrict__ tg,
    const float* __restrict__ alog, const float* __restrict__ theta,
    u16* __restrict__ z)
{
  const int bk = blockIdx.x;
  const int b = bk >> 5, k = bk & 31;
  const int j = threadIdx.x;
  const float a = 1.f / (1.f + __expf(-alog[k]));
  const float th = theta[k];
  const float wr = a * __cosf(th), wi = a * __sinf(th);
  const float* ubp = u_t + ((size_t)b * 32 + k) * 2048 + j * 8;
  float4 ua = ((const float4*)ubp)[0];
  float4 ub4 = ((const float4*)ubp)[1];
  float ur[8] = {ua.x, ua.y, ua.z, ua.w, ub4.x, ub4.y, ub4.z, ub4.w};
  float sr = 0.f, si = 0.f;
#pragma unroll
  for (int i = 0; i < 8; i++){
    float nr = wr*sr - wi*si + ur[i];
    float ni = wi*sr + wr*si;
    sr = nr; si = ni;
  }
  float w2r = wr*wr - wi*wi, w2i = 2.f*wr*wi;
  float w4r = w2r*w2r - w2i*w2i, w4i = 2.f*w2r*w2i;
  float Ar = w4r*w4r - w4i*w4i, Ai = 2.f*w4r*w4i;   // w^8
  __shared__ float4 sc[256];
  float4 cur; cur.x = Ar; cur.y = Ai; cur.z = sr; cur.w = si;
  sc[j] = cur;
  __syncthreads();
  for (int s = 1; s < 256; s <<= 1){
    float4 pv;
    const bool has = (j >= s);
    if (has) pv = sc[j - s];
    __syncthreads();
    if (has){
      float nar = cur.x*pv.x - cur.y*pv.y;
      float nai = cur.x*pv.y + cur.y*pv.x;
      float nbr = cur.x*pv.z - cur.y*pv.w + cur.z;
      float nbi = cur.x*pv.w + cur.y*pv.z + cur.w;
      cur.x = nar; cur.y = nai; cur.z = nbr; cur.w = nbi;
    }
    sc[j] = cur;
    __syncthreads();
  }
  float s_r = 0.f, s_i = 0.f;
  if (j > 0){ float4 pr = sc[j - 1]; s_r = pr.z; s_i = pr.w; }
  const float* tgp = tg + ((size_t)b * 2048 + j * 8) * 32 + k;
  u16* zp = z + ((size_t)b * 2048 + j * 8) * 32 + k;
#pragma unroll
  for (int i = 0; i < 8; i++){
    float nr = wr*s_r - wi*s_i + ur[i];
    float ni = wi*s_r + wr*s_i;
    s_r = nr; s_i = ni;
    zp[(size_t)i * 32] = f2b(s_r * tgp[(size_t)i * 32]);
  }
}

// ---------------------------------------------------------------------------
extern "C" void kernel_launch(void* const* d_in, const int* in_sizes, int n_in,
                              void* d_out, int out_size, void* d_ws, size_t ws_size,
                              hipStream_t stream)
{
  (void)in_sizes; (void)n_in; (void)out_size; (void)ws_size;
  const float* x      = (const float*)d_in[0];
  const float* n1w    = (const float*)d_in[1];
  const float* qkvw   = (const float*)d_in[2];
  const float* qkvb   = (const float*)d_in[3];
  const float* projw  = (const float*)d_in[4];
  const float* projb  = (const float*)d_in[5];
  const float* gatew  = (const float*)d_in[6];
  const float* gateb  = (const float*)d_in[7];
  const float* twin   = (const float*)d_in[8];
  const float* twout  = (const float*)d_in[9];
  const float* tgw    = (const float*)d_in[10];
  const float* tgb    = (const float*)d_in[11];
  const float* talog  = (const float*)d_in[12];
  const float* ttheta = (const float*)d_in[13];
  const float* tscale = (const float*)d_in[14];
  const float* n2w    = (const float*)d_in[15];
  const float* fgw    = (const float*)d_in[16];
  const float* fuw    = (const float*)d_in[17];
  const float* fdw    = (const float*)d_in[18];
  float* out = (float*)d_out;

  char* wsb = (char*)d_ws;
  size_t off = 0;
  auto take = [&](size_t bytes) -> void* {
    void* r = wsb + off; off += (bytes + 255) & ~(size_t)255; return r;
  };
  u16*   wall = (u16*)take(17041408ull * 2);   // packed bf16 weights
  u16*   h    = (u16*)take(4194304ull * 2);
  u16*   h2   = (u16*)take(4194304ull * 2);
  u16*   trn  = (u16*)take(4194304ull * 2);
  float* g    = (float*)take(4096ull * 4);
  float* xmid = (float*)take(4194304ull * 4);
  float* u_t  = (float*)take(131072ull * 4);
  float* tg   = (float*)take(131072ull * 4);
  u16*   zz   = (u16*)take(131072ull * 2);
  u16*   regA = (u16*)take(4096ull * 4096 * 2);  // qkv, later silu(gate)
  u16*   regB = (u16*)take(4096ull * 4096 * 2);  // ao,  later act

  u16* wq  = wall;
  u16* wp  = wall + 3145728;
  u16* wg  = wall + 4194304;
  u16* wu  = wall + 8388608;
  u16* wd  = wall + 12582912;
  u16* wct = wall + 16777216;   // [128][1024]: trn_win | trn_gate_w | zeros
  u16* wo  = wall + 16908288;   // [1024][32]
  u16* qkv = regA;
  u16* sg  = regA;
  u16* ao  = regB;
  u16* act = regB;

  convert_w<<<16642, 256, 0, stream>>>(qkvw, projw, fgw, fuw, fdw, twin, tgw, twout, wall);
  rmsnorm_gate<<<4096, 256, 0, stream>>>(x, n1w, gatew, gateb, h, g);
  // TRN drive u (-> [B,K,T]) and gate tg (-> [B*T,K])
  gemm_bt<5><<<dim3(32, 1), 256, 0, stream>>>(h, wct, u_t, tg, nullptr, tgb,
                                              nullptr, nullptr, nullptr, 4096, 128, 1024);
  scan_k<<<64, 256, 0, stream>>>(u_t, tg, talog, ttheta, zz);
  gemm_bt<6><<<dim3(32, 8), 256, 0, stream>>>(zz, wo, nullptr, nullptr, trn, nullptr,
                                              nullptr, tscale, nullptr, 4096, 1024, 32);
  // attention path
  gemm_bt<0><<<dim3(32, 24), 256, 0, stream>>>(h, wq, nullptr, nullptr, qkv, qkvb,
                                               nullptr, nullptr, nullptr, 4096, 3072, 1024);
  attn_win<<<1024, 256, 0, stream>>>(qkv, ao);
  // proj + gated mix -> xmid
  gemm_bt<4><<<dim3(32, 8), 256, 0, stream>>>(ao, wp, xmid, nullptr, nullptr, projb,
                                              trn, x, g, 4096, 1024, 1024);
  // FFN
  rmsnorm_plain<<<4096, 256, 0, stream>>>(xmid, n2w, h2);
  gemm_bt<1><<<dim3(32, 32), 256, 0, stream>>>(h2, wg, nullptr, nullptr, sg, nullptr,
                                               nullptr, nullptr, nullptr, 4096, 4096, 1024);
  gemm_bt<2><<<dim3(32, 32), 256, 0, stream>>>(h2, wu, nullptr, nullptr, act, nullptr,
                                               sg, nullptr, nullptr, 4096, 4096, 1024);
  gemm_bt<3><<<dim3(32, 8), 256, 0, stream>>>(act, wd, out, nullptr, nullptr, nullptr,
                                              nullptr, xmid, nullptr, 4096, 1024, 4096);
}

// Round 2
// 496.830 us; speedup vs baseline: 1.0219x; 1.0219x over previous
//
#include <hip/hip_runtime.h>

// DualMemoryBlock: rmsnorm -> {windowed attn, oscillator TRN} -> gated mix -> SwiGLU FFN
// bf16 MFMA 16x16x32, 128x128 tile, BK=32, global_load_lds(16B) staging.
// R2: split-K (blockIdx.z) for grid-starved GEMMs; merged gate+up GEMM (interleaved cols).

typedef unsigned short u16;
typedef unsigned short u16x8 __attribute__((ext_vector_type(8)));
typedef __bf16 bf16x8 __attribute__((ext_vector_type(8)));
typedef float f32x4 __attribute__((ext_vector_type(4)));

#define DI static __device__ __forceinline__

DI u16 f2b(float f){
  union { float f; unsigned u; } v; v.f = f;
  unsigned r = v.u + 0x7FFFu + ((v.u >> 16) & 1u);
  return (u16)(r >> 16);
}
DI float b2f(u16 b){
  union { unsigned u; float f; } v; v.u = ((unsigned)b) << 16; return v.f;
}
DI u16x8 ld8(const u16* p){ return *(const u16x8*)p; }

DI f32x4 MFMA16(u16x8 a, u16x8 b, f32x4 c){
  return __builtin_amdgcn_mfma_f32_16x16x32_bf16(
      __builtin_bit_cast(bf16x8, a), __builtin_bit_cast(bf16x8, b), c, 0, 0, 0);
}

DI void async16(const void* g, void* l){
  void* gg = const_cast<void*>(g);
  __builtin_amdgcn_global_load_lds(
      (__attribute__((address_space(1))) void*)gg,
      (__attribute__((address_space(3))) void*)l, 16, 0, 0);
}

// ---------------------------------------------------------------------------
// Weight conversion fp32 -> bf16 into one packed buffer.
// sections (elements): qkv 3145728 | proj 1048576 | ffn gate+up INTERLEAVED
//  (row 2n = gate n, row 2n+1 = up n) 8388608 | ffn_down 4194304 |
//  trn combined(128x1024: win|gate|zeros) 131072 | wout 32768 => 17041408
// ---------------------------------------------------------------------------
__global__ __launch_bounds__(256) void convert_w(
    const float* __restrict__ qkvw, const float* __restrict__ projw,
    const float* __restrict__ fgw, const float* __restrict__ fuw,
    const float* __restrict__ fdw, const float* __restrict__ twin,
    const float* __restrict__ tgw, const float* __restrict__ twout,
    u16* __restrict__ dst)
{
  size_t i = (size_t)blockIdx.x * 256 + threadIdx.x;
  if (i >= 4260352u) return;
  size_t e = i * 4;
  float4 v;
  if (e < 3145728u)        v = *(const float4*)(qkvw + e);
  else if (e < 4194304u)   v = *(const float4*)(projw + (e - 3145728u));
  else if (e < 12582912u){
    size_t i2 = e - 4194304u;
    int row = (int)(i2 >> 10), c = (int)(i2 & 1023);
    const float* src = (row & 1) ? fuw : fgw;
    v = *(const float4*)(src + (size_t)(row >> 1) * 1024 + c);
  }
  else if (e < 16777216u)  v = *(const float4*)(fdw + (e - 12582912u));
  else if (e < 16908288u){
    size_t i2 = e - 16777216u;
    int row = (int)(i2 >> 10), c = (int)(i2 & 1023);
    if (row < 32)      v = *(const float4*)(twin + row * 1024 + c);
    else if (row < 64) v = *(const float4*)(tgw + (row - 32) * 1024 + c);
    else               v = make_float4(0.f, 0.f, 0.f, 0.f);
  } else {
    v = *(const float4*)(twout + (e - 16908288u));
  }
  uint2 p;
  p.x = (unsigned)f2b(v.x) | ((unsigned)f2b(v.y) << 16);
  p.y = (unsigned)f2b(v.z) | ((unsigned)f2b(v.w) << 16);
  *(uint2*)(dst + e) = p;
}

// ---------------------------------------------------------------------------
__global__ __launch_bounds__(256) void zero_f32(float* __restrict__ p, int n4)
{
  int i = blockIdx.x * 256 + threadIdx.x;
  if (i < n4) ((float4*)p)[i] = make_float4(0.f, 0.f, 0.f, 0.f);
}

__global__ __launch_bounds__(256) void copy_f32(
    const float* __restrict__ src, float* __restrict__ dst)
{
  int i = blockIdx.x * 256 + threadIdx.x;
  ((float4*)dst)[i] = ((const float4*)src)[i];
}

// ---------------------------------------------------------------------------
// RMSNorm (+ fused scalar gate logit for norm1)
// ---------------------------------------------------------------------------
__global__ __launch_bounds__(256) void rmsnorm_gate(
    const float* __restrict__ x, const float* __restrict__ w,
    const float* __restrict__ gw, const float* __restrict__ gb,
    u16* __restrict__ h, float* __restrict__ g)
{
  const int row = blockIdx.x, tid = threadIdx.x;
  const int wave = tid >> 6, lane = tid & 63;
  __shared__ float sb[8];
  float4 xv = ((const float4*)(x + (size_t)row * 1024))[tid];
  float ss = xv.x*xv.x + xv.y*xv.y + xv.z*xv.z + xv.w*xv.w;
#pragma unroll
  for (int m = 32; m; m >>= 1) ss += __shfl_xor(ss, m);
  if (lane == 0) sb[wave] = ss;
  __syncthreads();
  float rstd = rsqrtf((sb[0]+sb[1]+sb[2]+sb[3]) * (1.f/1024.f) + 1e-6f);
  float4 wv = ((const float4*)w)[tid];
  float h0 = xv.x*rstd*wv.x, h1 = xv.y*rstd*wv.y;
  float h2v = xv.z*rstd*wv.z, h3 = xv.w*rstd*wv.w;
  uint2 pk;
  pk.x = (unsigned)f2b(h0) | ((unsigned)f2b(h1) << 16);
  pk.y = (unsigned)f2b(h2v) | ((unsigned)f2b(h3) << 16);
  ((uint2*)(h + (size_t)row * 1024))[tid] = pk;
  float4 gv = ((const float4*)gw)[tid];
  float gd = h0*gv.x + h1*gv.y + h2v*gv.z + h3*gv.w;
#pragma unroll
  for (int m = 32; m; m >>= 1) gd += __shfl_xor(gd, m);
  if (lane == 0) sb[4 + wave] = gd;
  __syncthreads();
  if (tid == 0) g[row] = 1.f / (1.f + __expf(-(sb[4]+sb[5]+sb[6]+sb[7] + gb[0])));
}

__global__ __launch_bounds__(256) void rmsnorm_plain(
    const float* __restrict__ x, const float* __restrict__ w, u16* __restrict__ h)
{
  const int row = blockIdx.x, tid = threadIdx.x;
  const int wave = tid >> 6, lane = tid & 63;
  __shared__ float sb[4];
  float4 xv = ((const float4*)(x + (size_t)row * 1024))[tid];
  float ss = xv.x*xv.x + xv.y*xv.y + xv.z*xv.z + xv.w*xv.w;
#pragma unroll
  for (int m = 32; m; m >>= 1) ss += __shfl_xor(ss, m);
  if (lane == 0) sb[wave] = ss;
  __syncthreads();
  float rstd = rsqrtf((sb[0]+sb[1]+sb[2]+sb[3]) * (1.f/1024.f) + 1e-6f);
  float4 wv = ((const float4*)w)[tid];
  uint2 pk;
  pk.x = (unsigned)f2b(xv.x*rstd*wv.x) | ((unsigned)f2b(xv.y*rstd*wv.y) << 16);
  pk.y = (unsigned)f2b(xv.z*rstd*wv.z) | ((unsigned)f2b(xv.w*rstd*wv.w) << 16);
  ((uint2*)(h + (size_t)row * 1024))[tid] = pk;
}

// ---------------------------------------------------------------------------
// GEMM: out[m,n] = sum_k A[m,k]*B[n,k]  (row-major bf16, fp32 accum)
// 128x128 tile, BK=32, 256 thr = 2x2 waves; split-K via blockIdx.z.
// MODE epilogues:
//  0: outB = bf16(v + bias[col])                          (qkv)
//  3: atomicAdd(outF[idx], v)      out pre-init with xmid (ffn down + residual)
//  4: outF = auxF + g*(v+bias) + (1-g)*trn                (proj + gated mix)
//  5: col<32 -> atomicAdd u[b,k,t]; col<64 -> atomicAdd tg-logit[rr,k]
//  6: outB = bf16(v * auxF[0])                            (trn_out, res_scale)
//  7: interleaved gate/up: outB[rr, col>>1] = silu(g)*u via shfl_xor(1)
// ---------------------------------------------------------------------------
template<int MODE>
__global__ __launch_bounds__(256) void gemm_bt(
    const u16* __restrict__ A, const u16* __restrict__ B,
    float* __restrict__ outF, float* __restrict__ outF2, u16* __restrict__ outB,
    const float* __restrict__ bias, const u16* __restrict__ aux16,
    const float* __restrict__ auxF, const float* __restrict__ auxG,
    int M, int N, int K)
{
  (void)M;
  __shared__ __align__(16) u16 sA[128 * 32];
  __shared__ __align__(16) u16 sB[128 * 32];
  const int tid = threadIdx.x;
  const int wave = tid >> 6, lane = tid & 63;
  const int lr = lane & 15, lq = lane >> 4;
  const int m0 = blockIdx.x * 128, n0 = blockIdx.y * 128;
  const int wm = (wave & 1) * 64, wn = (wave >> 1) * 64;
  const int ks = K / (int)gridDim.z;
  const int kbeg = (int)blockIdx.z * ks, kend = kbeg + ks;
  f32x4 acc[4][4] = {};
  const int srow = wave * 16 + (lane >> 2);
  const int scol = (lane & 3) * 8;
  const u16* gA = A + (size_t)(m0 + srow) * K + scol;
  const u16* gB = B + (size_t)(n0 + srow) * K + scol;
  u16* lA0 = &sA[(wave * 16) * 32];
  u16* lA1 = &sA[(64 + wave * 16) * 32];
  u16* lB0 = &sB[(wave * 16) * 32];
  u16* lB1 = &sB[(64 + wave * 16) * 32];
  const size_t K64 = (size_t)64 * K;

  for (int k0 = kbeg; k0 < kend; k0 += 32){
    async16(gA + k0,       lA0);
    async16(gA + K64 + k0, lA1);
    async16(gB + k0,       lB0);
    async16(gB + K64 + k0, lB1);
    __syncthreads();
    u16x8 af[4], bf[4];
#pragma unroll
    for (int i = 0; i < 4; i++) af[i] = ld8(&sA[(wm + i*16 + lr)*32 + lq*8]);
#pragma unroll
    for (int i = 0; i < 4; i++) bf[i] = ld8(&sB[(wn + i*16 + lr)*32 + lq*8]);
#pragma unroll
    for (int mi = 0; mi < 4; mi++)
#pragma unroll
      for (int ni = 0; ni < 4; ni++)
        acc[mi][ni] = MFMA16(af[mi], bf[ni], acc[mi][ni]);
    __syncthreads();
  }

  float scale6 = 0.f;
  if (MODE == 6) scale6 = auxF[0];

#pragma unroll
  for (int mi = 0; mi < 4; mi++){
    const int row = m0 + wm + mi*16 + lq*4;
#pragma unroll
    for (int ni = 0; ni < 4; ni++){
      const int col = n0 + wn + ni*16 + lr;
#pragma unroll
      for (int r = 0; r < 4; r++){
        const int rr = row + r;
        float v = acc[mi][ni][r];
        if (MODE == 0){
          outB[(size_t)rr * N + col] = f2b(v + bias[col]);
        } else if (MODE == 3){
          atomicAdd(&outF[(size_t)rr * N + col], v);
        } else if (MODE == 4){
          const size_t idx = (size_t)rr * N + col;
          float gg = auxG[rr];
          outF[idx] = auxF[idx] + gg * (v + bias[col]) + (1.f - gg) * b2f(aux16[idx]);
        } else if (MODE == 5){
          int bb = rr >> 11, tt = rr & 2047;
          if (col < 32) atomicAdd(&outF[((size_t)bb * 32 + col) * 2048 + tt], v);
          else if (col < 64) atomicAdd(&outF2[(size_t)rr * 32 + (col - 32)], v);
        } else if (MODE == 6){
          outB[(size_t)rr * N + col] = f2b(v * scale6);
        } else if (MODE == 7){
          float p = __shfl_xor(v, 1);
          float gval = (lr & 1) ? p : v;
          float uval = (lr & 1) ? v : p;
          float rv = gval / (1.f + __expf(-gval)) * uval;
          if (!(lr & 1))
            outB[(size_t)rr * (N >> 1) + (col >> 1)] = f2b(rv);
        }
      }
    }
  }
}

// ---------------------------------------------------------------------------
// Windowed causal flash attention. qkv: [B*T, 3072] bf16 (q|k|v, 16 heads x 64).
// ---------------------------------------------------------------------------
__global__ __launch_bounds__(256) void attn_win(
    const u16* __restrict__ qkv, u16* __restrict__ ao)
{
  const int blk = blockIdx.x;
  const int tile = blk & 31, hh = (blk >> 5) & 15, b = blk >> 9;
  const int t0 = tile * 64;
  const int tid = threadIdx.x, wave = tid >> 6, lane = tid & 63;
  const int lr = lane & 15, lq = lane >> 4;
  const int qt = t0 + wave * 16;
  __shared__ __align__(16) u16 sVt[64 * 40];      // V^T, padded stride 40
  __shared__ __align__(16) u16 sP[4][16 * 32];    // per-wave P buffer

  const u16* base = qkv + (size_t)b * 2048 * 3072 + hh * 64;
  const u16* qrow = base + (size_t)(qt + lr) * 3072 + lq * 8;
  u16x8 qf0 = ld8(qrow), qf1 = ld8(qrow + 32);
  const u16* kbase = base + 1024;
  const u16* vbase = base + 2048;

  f32x4 o0 = {0,0,0,0}, o1 = {0,0,0,0}, o2 = {0,0,0,0}, o3 = {0,0,0,0};
  float mrun[4] = {-1e30f, -1e30f, -1e30f, -1e30f};
  float lrun[4] = {0.f, 0.f, 0.f, 0.f};
  const float c1 = 0.125f * 1.44269504088896f;  // scale * log2(e)

  const int kb = (t0 >= 256) ? (t0 - 256) : 0;
  const int ntl = (t0 + 64 - kb) >> 5;
  for (int it = 0; it < ntl; ++it){
    const int kt = kb + it * 32;
    __syncthreads();                 // prev-iter LDS reads done
    if (tid < 128){                  // stage V^T (32 keys x 64 dims)
      const int key = tid & 31, dh = tid >> 5;
      const u16* gv = vbase + (size_t)(kt + key) * 3072 + dh * 16;
      u16x8 v0 = ld8(gv), v1 = ld8(gv + 8);
#pragma unroll
      for (int j = 0; j < 8; j++){
        sVt[(dh*16 + j)     * 40 + key] = v0[j];
        sVt[(dh*16 + 8 + j) * 40 + key] = v1[j];
      }
    }
    __syncthreads();
    const bool active = (kt < qt + 16) && (kt + 286 >= qt);
    if (!active) continue;           // both barriers are above: counts stay equal

    f32x4 s0 = {0,0,0,0}, s1 = {0,0,0,0};
    {
      const u16* kr = kbase + (size_t)(kt + lr) * 3072 + lq * 8;
      u16x8 k00 = ld8(kr), k01 = ld8(kr + 32);
      const u16* kr1 = kr + (size_t)16 * 3072;
      u16x8 k10 = ld8(kr1), k11 = ld8(kr1 + 32);
      s0 = MFMA16(qf0, k00, s0); s0 = MFMA16(qf1, k01, s0);
      s1 = MFMA16(qf0, k10, s1); s1 = MFMA16(qf1, k11, s1);
    }
    float al[4];
#pragma unroll
    for (int r = 0; r < 4; r++){
      const int q = qt + lq * 4 + r;
      const int ca = kt + lr, cb = kt + 16 + lr;
      float a0 = (ca <= q && ca + 255 >= q) ? s0[r] : -1e30f;
      float a1 = (cb <= q && cb + 255 >= q) ? s1[r] : -1e30f;
      float mx = fmaxf(a0, a1);
      mx = fmaxf(mx, __shfl_xor(mx, 1));
      mx = fmaxf(mx, __shfl_xor(mx, 2));
      mx = fmaxf(mx, __shfl_xor(mx, 4));
      mx = fmaxf(mx, __shfl_xor(mx, 8));
      float mn = fmaxf(mrun[r], mx);
      al[r] = exp2f((mrun[r] - mn) * c1);
      mrun[r] = mn;
      float p0 = (a0 > -1e29f) ? exp2f((a0 - mn) * c1) : 0.f;
      float p1 = (a1 > -1e29f) ? exp2f((a1 - mn) * c1) : 0.f;
      float sm = p0 + p1;
      sm += __shfl_xor(sm, 1); sm += __shfl_xor(sm, 2);
      sm += __shfl_xor(sm, 4); sm += __shfl_xor(sm, 8);
      lrun[r] = lrun[r] * al[r] + sm;
      sP[wave][(lq*4 + r) * 32 + lr]      = f2b(p0);
      sP[wave][(lq*4 + r) * 32 + 16 + lr] = f2b(p1);
    }
#pragma unroll
    for (int r = 0; r < 4; r++){
      o0[r] *= al[r]; o1[r] *= al[r]; o2[r] *= al[r]; o3[r] *= al[r];
    }
    __builtin_amdgcn_s_waitcnt(0xc07f);   // lgkmcnt(0): P writes visible
    u16x8 pf = ld8(&sP[wave][lr * 32 + lq * 8]);
    o0 = MFMA16(pf, ld8(&sVt[(lr)      * 40 + lq * 8]), o0);
    o1 = MFMA16(pf, ld8(&sVt[(16 + lr) * 40 + lq * 8]), o1);
    o2 = MFMA16(pf, ld8(&sVt[(32 + lr) * 40 + lq * 8]), o2);
    o3 = MFMA16(pf, ld8(&sVt[(48 + lr) * 40 + lq * 8]), o3);
  }

  u16* aor = ao + (size_t)(b * 2048 + qt + lq * 4) * 1024 + hh * 64 + lr;
#pragma unroll
  for (int r = 0; r < 4; r++){
    float inv = 1.f / lrun[r];
    u16* p = aor + (size_t)r * 1024;
    p[0]  = f2b(o0[r] * inv);
    p[16] = f2b(o1[r] * inv);
    p[32] = f2b(o2[r] * inv);
    p[48] = f2b(o3[r] * inv);
  }
}

// ---------------------------------------------------------------------------
// Oscillator scan. u from fp32 [B,K,T]; tg = sigmoid(tgl + tgb[k]) inline.
// ---------------------------------------------------------------------------
__global__ __launch_bounds__(256) void scan_k(
    const float* __restrict__ u_t, const float* __restrict__ tgl,
    const float* __restrict__ tgb,
    const float* __restrict__ alog, const float* __restrict__ theta,
    u16* __restrict__ z)
{
  const int bk = blockIdx.x;
  const int b = bk >> 5, k = bk & 31;
  const int j = threadIdx.x;
  const float a = 1.f / (1.f + __expf(-alog[k]));
  const float th = theta[k];
  const float bk_bias = tgb[k];
  const float wr = a * __cosf(th), wi = a * __sinf(th);
  const float* ubp = u_t + ((size_t)b * 32 + k) * 2048 + j * 8;
  float4 ua = ((const float4*)ubp)[0];
  float4 ub4 = ((const float4*)ubp)[1];
  float ur[8] = {ua.x, ua.y, ua.z, ua.w, ub4.x, ub4.y, ub4.z, ub4.w};
  float sr = 0.f, si = 0.f;
#pragma unroll
  for (int i = 0; i < 8; i++){
    float nr = wr*sr - wi*si + ur[i];
    float ni = wi*sr + wr*si;
    sr = nr; si = ni;
  }
  float w2r = wr*wr - wi*wi, w2i = 2.f*wr*wi;
  float w4r = w2r*w2r - w2i*w2i, w4i = 2.f*w2r*w2i;
  float Ar = w4r*w4r - w4i*w4i, Ai = 2.f*w4r*w4i;   // w^8
  __shared__ float4 sc[256];
  float4 cur; cur.x = Ar; cur.y = Ai; cur.z = sr; cur.w = si;
  sc[j] = cur;
  __syncthreads();
  for (int s = 1; s < 256; s <<= 1){
    float4 pv;
    const bool has = (j >= s);
    if (has) pv = sc[j - s];
    __syncthreads();
    if (has){
      float nar = cur.x*pv.x - cur.y*pv.y;
      float nai = cur.x*pv.y + cur.y*pv.x;
      float nbr = cur.x*pv.z - cur.y*pv.w + cur.z;
      float nbi = cur.x*pv.w + cur.y*pv.z + cur.w;
      cur.x = nar; cur.y = nai; cur.z = nbr; cur.w = nbi;
    }
    sc[j] = cur;
    __syncthreads();
  }
  float s_r = 0.f, s_i = 0.f;
  if (j > 0){ float4 pr = sc[j - 1]; s_r = pr.z; s_i = pr.w; }
  const float* tgp = tgl + ((size_t)b * 2048 + j * 8) * 32 + k;
  u16* zp = z + ((size_t)b * 2048 + j * 8) * 32 + k;
#pragma unroll
  for (int i = 0; i < 8; i++){
    float nr = wr*s_r - wi*s_i + ur[i];
    float ni = wi*s_r + wr*s_i;
    s_r = nr; s_i = ni;
    float tgv = 1.f / (1.f + __expf(-(tgp[(size_t)i * 32] + bk_bias)));
    zp[(size_t)i * 32] = f2b(s_r * tgv);
  }
}

// ---------------------------------------------------------------------------
extern "C" void kernel_launch(void* const* d_in, const int* in_sizes, int n_in,
                              void* d_out, int out_size, void* d_ws, size_t ws_size,
                              hipStream_t stream)
{
  (void)in_sizes; (void)n_in; (void)out_size; (void)ws_size;
  const float* x      = (const float*)d_in[0];
  const float* n1w    = (const float*)d_in[1];
  const float* qkvw   = (const float*)d_in[2];
  const float* qkvb   = (const float*)d_in[3];
  const float* projw  = (const float*)d_in[4];
  const float* projb  = (const float*)d_in[5];
  const float* gatew  = (const float*)d_in[6];
  const float* gateb  = (const float*)d_in[7];
  const float* twin   = (const float*)d_in[8];
  const float* twout  = (const float*)d_in[9];
  const float* tgw    = (const float*)d_in[10];
  const float* tgb    = (const float*)d_in[11];
  const float* talog  = (const float*)d_in[12];
  const float* ttheta = (const float*)d_in[13];
  const float* tscale = (const float*)d_in[14];
  const float* n2w    = (const float*)d_in[15];
  const float* fgw    = (const float*)d_in[16];
  const float* fuw    = (const float*)d_in[17];
  const float* fdw    = (const float*)d_in[18];
  float* out = (float*)d_out;

  char* wsb = (char*)d_ws;
  size_t off = 0;
  auto take = [&](size_t bytes) -> void* {
    void* r = wsb + off; off += (bytes + 255) & ~(size_t)255; return r;
  };
  u16*   wall = (u16*)take(17041408ull * 2);   // packed bf16 weights
  u16*   h    = (u16*)take(4194304ull * 2);
  u16*   h2   = (u16*)take(4194304ull * 2);
  u16*   trn  = (u16*)take(4194304ull * 2);
  float* g    = (float*)take(4096ull * 4);
  float* xmid = (float*)take(4194304ull * 4);
  float* uacc = (float*)take(262144ull * 4);   // u [B,K,T] fp32 + tg-logit [B*T,K]
  float* tgl  = uacc + 131072;
  u16*   zz   = (u16*)take(131072ull * 2);
  u16*   regA = (u16*)take(4096ull * 4096 * 2);  // qkv, later act
  u16*   regB = (u16*)take(4096ull * 4096 * 2);  // ao

  u16* wq  = wall;
  u16* wp  = wall + 3145728;
  u16* wgu = wall + 4194304;    // [8192][1024] interleaved gate/up
  u16* wd  = wall + 12582912;   // [1024][4096]
  u16* wct = wall + 16777216;   // [128][1024]: trn_win | trn_gate_w | zeros
  u16* wo  = wall + 16908288;   // [1024][32]
  u16* qkv = regA;
  u16* act = regA;
  u16* ao  = regB;

  convert_w<<<16642, 256, 0, stream>>>(qkvw, projw, fgw, fuw, fdw, twin, tgw, twout, wall);
  rmsnorm_gate<<<4096, 256, 0, stream>>>(x, n1w, gatew, gateb, h, g);
  // TRN drive u + gate logits (split-K x8, atomic accumulate into zeroed bufs)
  zero_f32<<<256, 256, 0, stream>>>(uacc, 65536);
  gemm_bt<5><<<dim3(32, 1, 8), 256, 0, stream>>>(h, wct, uacc, tgl, nullptr, nullptr,
                                                 nullptr, nullptr, nullptr, 4096, 128, 1024);
  scan_k<<<64, 256, 0, stream>>>(uacc, tgl, tgb, talog, ttheta, zz);
  gemm_bt<6><<<dim3(32, 8), 256, 0, stream>>>(zz, wo, nullptr, nullptr, trn, nullptr,
                                              nullptr, tscale, nullptr, 4096, 1024, 32);
  // attention path
  gemm_bt<0><<<dim3(32, 24), 256, 0, stream>>>(h, wq, nullptr, nullptr, qkv, qkvb,
                                               nullptr, nullptr, nullptr, 4096, 3072, 1024);
  attn_win<<<1024, 256, 0, stream>>>(qkv, ao);
  // proj + gated mix -> xmid
  gemm_bt<4><<<dim3(32, 8), 256, 0, stream>>>(ao, wp, xmid, nullptr, nullptr, projb,
                                              trn, x, g, 4096, 1024, 1024);
  // FFN
  rmsnorm_plain<<<4096, 256, 0, stream>>>(xmid, n2w, h2);
  gemm_bt<7><<<dim3(32, 64), 256, 0, stream>>>(h2, wgu, nullptr, nullptr, act, nullptr,
                                               nullptr, nullptr, nullptr, 4096, 8192, 1024);
  copy_f32<<<4096, 256, 0, stream>>>(xmid, out);
  gemm_bt<3><<<dim3(32, 8, 4), 256, 0, stream>>>(act, wd, out, nullptr, nullptr, nullptr,
                                                 nullptr, nullptr, nullptr, 4096, 1024, 4096);
}

// Round 3
// 449.576 us; speedup vs baseline: 1.1293x; 1.1051x over previous
//
#include <hip/hip_runtime.h>

// DualMemoryBlock: rmsnorm -> {windowed attn, oscillator TRN} -> gated mix -> SwiGLU FFN
// bf16 MFMA 16x16x32, 128x128 tile, BK=32, global_load_lds(16B) staging.
// R3: gate/up group-interleave (shfl-free epilogue, dense stores); split-K via
// deterministic partials + fused reduce kernels (proj+mix+rmsnorm2, down+residual).

typedef unsigned short u16;
typedef unsigned short u16x8 __attribute__((ext_vector_type(8)));
typedef __bf16 bf16x8 __attribute__((ext_vector_type(8)));
typedef float f32x4 __attribute__((ext_vector_type(4)));

#define DI static __device__ __forceinline__

DI u16 f2b(float f){
  union { float f; unsigned u; } v; v.f = f;
  unsigned r = v.u + 0x7FFFu + ((v.u >> 16) & 1u);
  return (u16)(r >> 16);
}
DI float b2f(u16 b){
  union { unsigned u; float f; } v; v.u = ((unsigned)b) << 16; return v.f;
}
DI u16x8 ld8(const u16* p){ return *(const u16x8*)p; }

DI f32x4 MFMA16(u16x8 a, u16x8 b, f32x4 c){
  return __builtin_amdgcn_mfma_f32_16x16x32_bf16(
      __builtin_bit_cast(bf16x8, a), __builtin_bit_cast(bf16x8, b), c, 0, 0, 0);
}

DI void async16(const void* g, void* l){
  void* gg = const_cast<void*>(g);
  __builtin_amdgcn_global_load_lds(
      (__attribute__((address_space(1))) void*)gg,
      (__attribute__((address_space(3))) void*)l, 16, 0, 0);
}

// ---------------------------------------------------------------------------
// Weight conversion fp32 -> bf16 into one packed buffer.
// sections (elements): qkv 3145728 | proj 1048576 | ffn gate+up GROUP-interleaved
//  (32-row groups: rows 0-15 = gate cols g*16+j, rows 16-31 = up same cols)
//  8388608 | ffn_down 4194304 | trn combined(128x1024) 131072 | wout 32768
// ---------------------------------------------------------------------------
__global__ __launch_bounds__(256) void convert_w(
    const float* __restrict__ qkvw, const float* __restrict__ projw,
    const float* __restrict__ fgw, const float* __restrict__ fuw,
    const float* __restrict__ fdw, const float* __restrict__ twin,
    const float* __restrict__ tgw, const float* __restrict__ twout,
    u16* __restrict__ dst)
{
  size_t i = (size_t)blockIdx.x * 256 + threadIdx.x;
  if (i >= 4260352u) return;
  size_t e = i * 4;
  float4 v;
  if (e < 3145728u)        v = *(const float4*)(qkvw + e);
  else if (e < 4194304u)   v = *(const float4*)(projw + (e - 3145728u));
  else if (e < 12582912u){
    size_t i2 = e - 4194304u;
    int row = (int)(i2 >> 10), c = (int)(i2 & 1023);
    int G = row >> 5, j = row & 31;
    const float* src = (j < 16) ? fgw : fuw;
    v = *(const float4*)(src + (size_t)(G * 16 + (j & 15)) * 1024 + c);
  }
  else if (e < 16777216u)  v = *(const float4*)(fdw + (e - 12582912u));
  else if (e < 16908288u){
    size_t i2 = e - 16777216u;
    int row = (int)(i2 >> 10), c = (int)(i2 & 1023);
    if (row < 32)      v = *(const float4*)(twin + row * 1024 + c);
    else if (row < 64) v = *(const float4*)(tgw + (row - 32) * 1024 + c);
    else               v = make_float4(0.f, 0.f, 0.f, 0.f);
  } else {
    v = *(const float4*)(twout + (e - 16908288u));
  }
  uint2 p;
  p.x = (unsigned)f2b(v.x) | ((unsigned)f2b(v.y) << 16);
  p.y = (unsigned)f2b(v.z) | ((unsigned)f2b(v.w) << 16);
  *(uint2*)(dst + e) = p;
}

// ---------------------------------------------------------------------------
__global__ __launch_bounds__(256) void zero_f32(float* __restrict__ p, int n4)
{
  int i = blockIdx.x * 256 + threadIdx.x;
  if (i < n4) ((float4*)p)[i] = make_float4(0.f, 0.f, 0.f, 0.f);
}

// ---------------------------------------------------------------------------
// RMSNorm (+ fused scalar gate logit for norm1)
// ---------------------------------------------------------------------------
__global__ __launch_bounds__(256) void rmsnorm_gate(
    const float* __restrict__ x, const float* __restrict__ w,
    const float* __restrict__ gw, const float* __restrict__ gb,
    u16* __restrict__ h, float* __restrict__ g)
{
  const int row = blockIdx.x, tid = threadIdx.x;
  const int wave = tid >> 6, lane = tid & 63;
  __shared__ float sb[8];
  float4 xv = ((const float4*)(x + (size_t)row * 1024))[tid];
  float ss = xv.x*xv.x + xv.y*xv.y + xv.z*xv.z + xv.w*xv.w;
#pragma unroll
  for (int m = 32; m; m >>= 1) ss += __shfl_xor(ss, m);
  if (lane == 0) sb[wave] = ss;
  __syncthreads();
  float rstd = rsqrtf((sb[0]+sb[1]+sb[2]+sb[3]) * (1.f/1024.f) + 1e-6f);
  float4 wv = ((const float4*)w)[tid];
  float h0 = xv.x*rstd*wv.x, h1 = xv.y*rstd*wv.y;
  float h2v = xv.z*rstd*wv.z, h3 = xv.w*rstd*wv.w;
  uint2 pk;
  pk.x = (unsigned)f2b(h0) | ((unsigned)f2b(h1) << 16);
  pk.y = (unsigned)f2b(h2v) | ((unsigned)f2b(h3) << 16);
  ((uint2*)(h + (size_t)row * 1024))[tid] = pk;
  float4 gv = ((const float4*)gw)[tid];
  float gd = h0*gv.x + h1*gv.y + h2v*gv.z + h3*gv.w;
#pragma unroll
  for (int m = 32; m; m >>= 1) gd += __shfl_xor(gd, m);
  if (lane == 0) sb[4 + wave] = gd;
  __syncthreads();
  if (tid == 0) g[row] = 1.f / (1.f + __expf(-(sb[4]+sb[5]+sb[6]+sb[7] + gb[0])));
}

// ---------------------------------------------------------------------------
// Fused: proj split-K reduce + bias + gated mix + rmsnorm2.
// xmid = x + g*(p0+p1+projb) + (1-g)*trn ; h2 = bf16(rms(xmid)*n2w)
// ---------------------------------------------------------------------------
__global__ __launch_bounds__(256) void reduce_mix_norm(
    const float* __restrict__ part, const float* __restrict__ x,
    const u16* __restrict__ trn, const float* __restrict__ g,
    const float* __restrict__ pb, const float* __restrict__ n2w,
    float* __restrict__ xmid, u16* __restrict__ h2)
{
  const int row = blockIdx.x, tid = threadIdx.x;
  const int wave = tid >> 6, lane = tid & 63;
  __shared__ float sb[4];
  const size_t ro = (size_t)row * 1024;
  float4 p0 = ((const float4*)(part + ro))[tid];
  float4 p1 = ((const float4*)(part + 4194304 + ro))[tid];
  float4 bb = ((const float4*)pb)[tid];
  float4 xv = ((const float4*)(x + ro))[tid];
  uint2 tz = ((const uint2*)(trn + ro))[tid];
  float gg = g[row];
  float t0 = b2f((u16)tz.x), t1 = b2f((u16)(tz.x >> 16));
  float t2 = b2f((u16)tz.y), t3 = b2f((u16)(tz.y >> 16));
  float m0 = xv.x + gg*(p0.x+p1.x+bb.x) + (1.f-gg)*t0;
  float m1 = xv.y + gg*(p0.y+p1.y+bb.y) + (1.f-gg)*t1;
  float m2 = xv.z + gg*(p0.z+p1.z+bb.z) + (1.f-gg)*t2;
  float m3 = xv.w + gg*(p0.w+p1.w+bb.w) + (1.f-gg)*t3;
  float4 mo; mo.x = m0; mo.y = m1; mo.z = m2; mo.w = m3;
  ((float4*)(xmid + ro))[tid] = mo;
  float ss = m0*m0 + m1*m1 + m2*m2 + m3*m3;
#pragma unroll
  for (int m = 32; m; m >>= 1) ss += __shfl_xor(ss, m);
  if (lane == 0) sb[wave] = ss;
  __syncthreads();
  float rstd = rsqrtf((sb[0]+sb[1]+sb[2]+sb[3]) * (1.f/1024.f) + 1e-6f);
  float4 wv = ((const float4*)n2w)[tid];
  uint2 pk;
  pk.x = (unsigned)f2b(m0*rstd*wv.x) | ((unsigned)f2b(m1*rstd*wv.y) << 16);
  pk.y = (unsigned)f2b(m2*rstd*wv.z) | ((unsigned)f2b(m3*rstd*wv.w) << 16);
  ((uint2*)(h2 + ro))[tid] = pk;
}

// Fused: down split-K reduce + residual. out = xmid + p0 + p1
__global__ __launch_bounds__(256) void reduce_down(
    const float* __restrict__ part, const float* __restrict__ xmid,
    float* __restrict__ out)
{
  size_t i = (size_t)blockIdx.x * 256 + threadIdx.x;
  float4 p0 = ((const float4*)part)[i];
  float4 p1 = ((const float4*)(part + 4194304))[i];
  float4 xv = ((const float4*)xmid)[i];
  float4 o;
  o.x = xv.x + p0.x + p1.x; o.y = xv.y + p0.y + p1.y;
  o.z = xv.z + p0.z + p1.z; o.w = xv.w + p0.w + p1.w;
  ((float4*)out)[i] = o;
}

// ---------------------------------------------------------------------------
// GEMM: out[m,n] = sum_k A[m,k]*B[n,k]  (row-major bf16, fp32 accum)
// 128x128 tile, BK=32, 256 thr = 2x2 waves; split-K via blockIdx.z.
// MODE epilogues:
//  0: outB = bf16(v + bias[col])                          (qkv)
//  5: col<32 -> atomicAdd u[b,k,t]; col<64 -> atomicAdd tg-logit[rr,k]
//  6: outB = bf16(v * auxF[0])                            (trn_out, res_scale)
//  7: grouped gate/up: silu(acc[.][2p])*acc[.][2p+1], all lanes store
//  8: partial fp32 store at z*M + rr*N + col              (split-K partials)
// ---------------------------------------------------------------------------
template<int MODE>
__global__ __launch_bounds__(256) void gemm_bt(
    const u16* __restrict__ A, const u16* __restrict__ B,
    float* __restrict__ outF, float* __restrict__ outF2, u16* __restrict__ outB,
    const float* __restrict__ bias, const float* __restrict__ auxF,
    int M, int N, int K)
{
  __shared__ __align__(16) u16 sA[128 * 32];
  __shared__ __align__(16) u16 sB[128 * 32];
  const int tid = threadIdx.x;
  const int wave = tid >> 6, lane = tid & 63;
  const int lr = lane & 15, lq = lane >> 4;
  const int m0 = blockIdx.x * 128, n0 = blockIdx.y * 128;
  const int wm = (wave & 1) * 64, wn = (wave >> 1) * 64;
  const int ks = K / (int)gridDim.z;
  const int kbeg = (int)blockIdx.z * ks, kend = kbeg + ks;
  f32x4 acc[4][4] = {};
  const int srow = wave * 16 + (lane >> 2);
  const int scol = (lane & 3) * 8;
  const u16* gA = A + (size_t)(m0 + srow) * K + scol;
  const u16* gB = B + (size_t)(n0 + srow) * K + scol;
  u16* lA0 = &sA[(wave * 16) * 32];
  u16* lA1 = &sA[(64 + wave * 16) * 32];
  u16* lB0 = &sB[(wave * 16) * 32];
  u16* lB1 = &sB[(64 + wave * 16) * 32];
  const size_t K64 = (size_t)64 * K;

  for (int k0 = kbeg; k0 < kend; k0 += 32){
    async16(gA + k0,       lA0);
    async16(gA + K64 + k0, lA1);
    async16(gB + k0,       lB0);
    async16(gB + K64 + k0, lB1);
    __syncthreads();
    u16x8 af[4], bf[4];
#pragma unroll
    for (int i = 0; i < 4; i++) af[i] = ld8(&sA[(wm + i*16 + lr)*32 + lq*8]);
#pragma unroll
    for (int i = 0; i < 4; i++) bf[i] = ld8(&sB[(wn + i*16 + lr)*32 + lq*8]);
#pragma unroll
    for (int mi = 0; mi < 4; mi++)
#pragma unroll
      for (int ni = 0; ni < 4; ni++)
        acc[mi][ni] = MFMA16(af[mi], bf[ni], acc[mi][ni]);
    __syncthreads();
  }

  if (MODE == 7){
    // gate = acc[mi][2p], up = acc[mi][2p+1] for same 16 output cols
    const int cb = ((n0 + wn) >> 1) + lr;   // packed col base
#pragma unroll
    for (int mi = 0; mi < 4; mi++){
      const int row = m0 + wm + mi*16 + lq*4;
#pragma unroll
      for (int p = 0; p < 2; p++){
        const int col = cb + p*16;
#pragma unroll
        for (int r = 0; r < 4; r++){
          float gv = acc[mi][2*p][r], uv = acc[mi][2*p+1][r];
          float rv = gv / (1.f + __expf(-gv)) * uv;
          outB[(size_t)(row + r) * (N >> 1) + col] = f2b(rv);
        }
      }
    }
    return;
  }

  float scale6 = 0.f;
  if (MODE == 6) scale6 = auxF[0];

#pragma unroll
  for (int mi = 0; mi < 4; mi++){
    const int row = m0 + wm + mi*16 + lq*4;
#pragma unroll
    for (int ni = 0; ni < 4; ni++){
      const int col = n0 + wn + ni*16 + lr;
#pragma unroll
      for (int r = 0; r < 4; r++){
        const int rr = row + r;
        float v = acc[mi][ni][r];
        if (MODE == 0){
          outB[(size_t)rr * N + col] = f2b(v + bias[col]);
        } else if (MODE == 5){
          int bb = rr >> 11, tt = rr & 2047;
          if (col < 32) atomicAdd(&outF[((size_t)bb * 32 + col) * 2048 + tt], v);
          else if (col < 64) atomicAdd(&outF2[(size_t)rr * 32 + (col - 32)], v);
        } else if (MODE == 6){
          outB[(size_t)rr * N + col] = f2b(v * scale6);
        } else if (MODE == 8){
          outF[(size_t)blockIdx.z * (size_t)M + (size_t)rr * N + col] = v;
        }
      }
    }
  }
}

// ---------------------------------------------------------------------------
// Windowed causal flash attention. qkv: [B*T, 3072] bf16 (q|k|v, 16 heads x 64).
// ---------------------------------------------------------------------------
__global__ __launch_bounds__(256) void attn_win(
    const u16* __restrict__ qkv, u16* __restrict__ ao)
{
  const int blk = blockIdx.x;
  const int tile = blk & 31, hh = (blk >> 5) & 15, b = blk >> 9;
  const int t0 = tile * 64;
  const int tid = threadIdx.x, wave = tid >> 6, lane = tid & 63;
  const int lr = lane & 15, lq = lane >> 4;
  const int qt = t0 + wave * 16;
  __shared__ __align__(16) u16 sVt[64 * 40];      // V^T, padded stride 40
  __shared__ __align__(16) u16 sP[4][16 * 32];    // per-wave P buffer

  const u16* base = qkv + (size_t)b * 2048 * 3072 + hh * 64;
  const u16* qrow = base + (size_t)(qt + lr) * 3072 + lq * 8;
  u16x8 qf0 = ld8(qrow), qf1 = ld8(qrow + 32);
  const u16* kbase = base + 1024;
  const u16* vbase = base + 2048;

  f32x4 o0 = {0,0,0,0}, o1 = {0,0,0,0}, o2 = {0,0,0,0}, o3 = {0,0,0,0};
  float mrun[4] = {-1e30f, -1e30f, -1e30f, -1e30f};
  float lrun[4] = {0.f, 0.f, 0.f, 0.f};
  const float c1 = 0.125f * 1.44269504088896f;  // scale * log2(e)

  const int kb = (t0 >= 256) ? (t0 - 256) : 0;
  const int ntl = (t0 + 64 - kb) >> 5;
  for (int it = 0; it < ntl; ++it){
    const int kt = kb + it * 32;
    __syncthreads();                 // prev-iter LDS reads done
    if (tid < 128){                  // stage V^T (32 keys x 64 dims)
      const int key = tid & 31, dh = tid >> 5;
      const u16* gv = vbase + (size_t)(kt + key) * 3072 + dh * 16;
      u16x8 v0 = ld8(gv), v1 = ld8(gv + 8);
#pragma unroll
      for (int j = 0; j < 8; j++){
        sVt[(dh*16 + j)     * 40 + key] = v0[j];
        sVt[(dh*16 + 8 + j) * 40 + key] = v1[j];
      }
    }
    __syncthreads();
    const bool active = (kt < qt + 16) && (kt + 286 >= qt);
    if (!active) continue;           // both barriers are above: counts stay equal

    f32x4 s0 = {0,0,0,0}, s1 = {0,0,0,0};
    {
      const u16* kr = kbase + (size_t)(kt + lr) * 3072 + lq * 8;
      u16x8 k00 = ld8(kr), k01 = ld8(kr + 32);
      const u16* kr1 = kr + (size_t)16 * 3072;
      u16x8 k10 = ld8(kr1), k11 = ld8(kr1 + 32);
      s0 = MFMA16(qf0, k00, s0); s0 = MFMA16(qf1, k01, s0);
      s1 = MFMA16(qf0, k10, s1); s1 = MFMA16(qf1, k11, s1);
    }
    float al[4];
#pragma unroll
    for (int r = 0; r < 4; r++){
      const int q = qt + lq * 4 + r;
      const int ca = kt + lr, cb = kt + 16 + lr;
      float a0 = (ca <= q && ca + 255 >= q) ? s0[r] : -1e30f;
      float a1 = (cb <= q && cb + 255 >= q) ? s1[r] : -1e30f;
      float mx = fmaxf(a0, a1);
      mx = fmaxf(mx, __shfl_xor(mx, 1));
      mx = fmaxf(mx, __shfl_xor(mx, 2));
      mx = fmaxf(mx, __shfl_xor(mx, 4));
      mx = fmaxf(mx, __shfl_xor(mx, 8));
      float mn = fmaxf(mrun[r], mx);
      al[r] = exp2f((mrun[r] - mn) * c1);
      mrun[r] = mn;
      float p0 = (a0 > -1e29f) ? exp2f((a0 - mn) * c1) : 0.f;
      float p1 = (a1 > -1e29f) ? exp2f((a1 - mn) * c1) : 0.f;
      float sm = p0 + p1;
      sm += __shfl_xor(sm, 1); sm += __shfl_xor(sm, 2);
      sm += __shfl_xor(sm, 4); sm += __shfl_xor(sm, 8);
      lrun[r] = lrun[r] * al[r] + sm;
      sP[wave][(lq*4 + r) * 32 + lr]      = f2b(p0);
      sP[wave][(lq*4 + r) * 32 + 16 + lr] = f2b(p1);
    }
#pragma unroll
    for (int r = 0; r < 4; r++){
      o0[r] *= al[r]; o1[r] *= al[r]; o2[r] *= al[r]; o3[r] *= al[r];
    }
    __builtin_amdgcn_s_waitcnt(0xc07f);   // lgkmcnt(0): P writes visible
    u16x8 pf = ld8(&sP[wave][lr * 32 + lq * 8]);
    o0 = MFMA16(pf, ld8(&sVt[(lr)      * 40 + lq * 8]), o0);
    o1 = MFMA16(pf, ld8(&sVt[(16 + lr) * 40 + lq * 8]), o1);
    o2 = MFMA16(pf, ld8(&sVt[(32 + lr) * 40 + lq * 8]), o2);
    o3 = MFMA16(pf, ld8(&sVt[(48 + lr) * 40 + lq * 8]), o3);
  }

  u16* aor = ao + (size_t)(b * 2048 + qt + lq * 4) * 1024 + hh * 64 + lr;
#pragma unroll
  for (int r = 0; r < 4; r++){
    float inv = 1.f / lrun[r];
    u16* p = aor + (size_t)r * 1024;
    p[0]  = f2b(o0[r] * inv);
    p[16] = f2b(o1[r] * inv);
    p[32] = f2b(o2[r] * inv);
    p[48] = f2b(o3[r] * inv);
  }
}

// ---------------------------------------------------------------------------
// Oscillator scan. u from fp32 [B,K,T]; tg = sigmoid(tgl + tgb[k]) inline.
// ---------------------------------------------------------------------------
__global__ __launch_bounds__(256) void scan_k(
    const float* __restrict__ u_t, const float* __restrict__ tgl,
    const float* __restrict__ tgb,
    const float* __restrict__ alog, const float* __restrict__ theta,
    u16* __restrict__ z)
{
  const int bk = blockIdx.x;
  const int b = bk >> 5, k = bk & 31;
  const int j = threadIdx.x;
  const float a = 1.f / (1.f + __expf(-alog[k]));
  const float th = theta[k];
  const float bk_bias = tgb[k];
  const float wr = a * __cosf(th), wi = a * __sinf(th);
  const float* ubp = u_t + ((size_t)b * 32 + k) * 2048 + j * 8;
  float4 ua = ((const float4*)ubp)[0];
  float4 ub4 = ((const float4*)ubp)[1];
  float ur[8] = {ua.x, ua.y, ua.z, ua.w, ub4.x, ub4.y, ub4.z, ub4.w};
  float sr = 0.f, si = 0.f;
#pragma unroll
  for (int i = 0; i < 8; i++){
    float nr = wr*sr - wi*si + ur[i];
    float ni = wi*sr + wr*si;
    sr = nr; si = ni;
  }
  float w2r = wr*wr - wi*wi, w2i = 2.f*wr*wi;
  float w4r = w2r*w2r - w2i*w2i, w4i = 2.f*w2r*w2i;
  float Ar = w4r*w4r - w4i*w4i, Ai = 2.f*w4r*w4i;   // w^8
  __shared__ float4 sc[256];
  float4 cur; cur.x = Ar; cur.y = Ai; cur.z = sr; cur.w = si;
  sc[j] = cur;
  __syncthreads();
  for (int s = 1; s < 256; s <<= 1){
    float4 pv;
    const bool has = (j >= s);
    if (has) pv = sc[j - s];
    __syncthreads();
    if (has){
      float nar = cur.x*pv.x - cur.y*pv.y;
      float nai = cur.x*pv.y + cur.y*pv.x;
      float nbr = cur.x*pv.z - cur.y*pv.w + cur.z;
      float nbi = cur.x*pv.w + cur.y*pv.z + cur.w;
      cur.x = nar; cur.y = nai; cur.z = nbr; cur.w = nbi;
    }
    sc[j] = cur;
    __syncthreads();
  }
  float s_r = 0.f, s_i = 0.f;
  if (j > 0){ float4 pr = sc[j - 1]; s_r = pr.z; s_i = pr.w; }
  const float* tgp = tgl + ((size_t)b * 2048 + j * 8) * 32 + k;
  u16* zp = z + ((size_t)b * 2048 + j * 8) * 32 + k;
#pragma unroll
  for (int i = 0; i < 8; i++){
    float nr = wr*s_r - wi*s_i + ur[i];
    float ni = wi*s_r + wr*s_i;
    s_r = nr; s_i = ni;
    float tgv = 1.f / (1.f + __expf(-(tgp[(size_t)i * 32] + bk_bias)));
    zp[(size_t)i * 32] = f2b(s_r * tgv);
  }
}

// ---------------------------------------------------------------------------
extern "C" void kernel_launch(void* const* d_in, const int* in_sizes, int n_in,
                              void* d_out, int out_size, void* d_ws, size_t ws_size,
                              hipStream_t stream)
{
  (void)in_sizes; (void)n_in; (void)out_size; (void)ws_size;
  const float* x      = (const float*)d_in[0];
  const float* n1w    = (const float*)d_in[1];
  const float* qkvw   = (const float*)d_in[2];
  const float* qkvb   = (const float*)d_in[3];
  const float* projw  = (const float*)d_in[4];
  const float* projb  = (const float*)d_in[5];
  const float* gatew  = (const float*)d_in[6];
  const float* gateb  = (const float*)d_in[7];
  const float* twin   = (const float*)d_in[8];
  const float* twout  = (const float*)d_in[9];
  const float* tgw    = (const float*)d_in[10];
  const float* tgb    = (const float*)d_in[11];
  const float* talog  = (const float*)d_in[12];
  const float* ttheta = (const float*)d_in[13];
  const float* tscale = (const float*)d_in[14];
  const float* n2w    = (const float*)d_in[15];
  const float* fgw    = (const float*)d_in[16];
  const float* fuw    = (const float*)d_in[17];
  const float* fdw    = (const float*)d_in[18];
  float* out = (float*)d_out;

  char* wsb = (char*)d_ws;
  size_t off = 0;
  auto take = [&](size_t bytes) -> void* {
    void* r = wsb + off; off += (bytes + 255) & ~(size_t)255; return r;
  };
  u16*   wall = (u16*)take(17041408ull * 2);   // packed bf16 weights
  u16*   h    = (u16*)take(4194304ull * 2);
  u16*   h2   = (u16*)take(4194304ull * 2);
  u16*   trn  = (u16*)take(4194304ull * 2);
  float* g    = (float*)take(4096ull * 4);
  float* xmid = (float*)take(4194304ull * 4);
  float* uacc = (float*)take(262144ull * 4);   // u [B,K,T] fp32 + tg-logit [B*T,K]
  float* tgl  = uacc + 131072;
  u16*   zz   = (u16*)take(131072ull * 2);
  u16*   regA = (u16*)take(4096ull * 4096 * 2);  // qkv -> proj partials -> act
  u16*   regB = (u16*)take(4096ull * 4096 * 2);  // ao  -> down partials

  u16* wq  = wall;
  u16* wp  = wall + 3145728;
  u16* wgu = wall + 4194304;    // [8192][1024] group-interleaved gate/up
  u16* wd  = wall + 12582912;   // [1024][4096]
  u16* wct = wall + 16777216;   // [128][1024]: trn_win | trn_gate_w | zeros
  u16* wo  = wall + 16908288;   // [1024][32]
  u16*   qkv   = regA;
  float* pproj = (float*)regA;  // 2 x 4096x1024 fp32 = 33.55 MB (== regA size)
  u16*   act   = regA;
  u16*   ao    = regB;
  float* pdown = (float*)regB;

  convert_w<<<16642, 256, 0, stream>>>(qkvw, projw, fgw, fuw, fdw, twin, tgw, twout, wall);
  rmsnorm_gate<<<4096, 256, 0, stream>>>(x, n1w, gatew, gateb, h, g);
  // TRN drive u + gate logits (split-K x8, atomic accumulate into zeroed bufs)
  zero_f32<<<256, 256, 0, stream>>>(uacc, 65536);
  gemm_bt<5><<<dim3(32, 1, 8), 256, 0, stream>>>(h, wct, uacc, tgl, nullptr, nullptr,
                                                 nullptr, 0, 128, 1024);
  scan_k<<<64, 256, 0, stream>>>(uacc, tgl, tgb, talog, ttheta, zz);
  gemm_bt<6><<<dim3(32, 8), 256, 0, stream>>>(zz, wo, nullptr, nullptr, trn, nullptr,
                                              tscale, 0, 1024, 32);
  // attention path
  gemm_bt<0><<<dim3(32, 24), 256, 0, stream>>>(h, wq, nullptr, nullptr, qkv, qkvb,
                                               nullptr, 0, 3072, 1024);
  attn_win<<<1024, 256, 0, stream>>>(qkv, ao);
  // proj split-K2 -> partials, then fused reduce+mix+rmsnorm2
  gemm_bt<8><<<dim3(32, 8, 2), 256, 0, stream>>>(ao, wp, pproj, nullptr, nullptr, nullptr,
                                                 nullptr, 4194304, 1024, 1024);
  reduce_mix_norm<<<4096, 256, 0, stream>>>(pproj, x, trn, g, projb, n2w, xmid, h2);
  // FFN: merged gate+up (group-interleaved), then down split-K2 + fused residual
  gemm_bt<7><<<dim3(32, 64), 256, 0, stream>>>(h2, wgu, nullptr, nullptr, act, nullptr,
                                               nullptr, 0, 8192, 1024);
  gemm_bt<8><<<dim3(32, 8, 2), 256, 0, stream>>>(act, wd, pdown, nullptr, nullptr, nullptr,
                                                 nullptr, 4194304, 1024, 4096);
  reduce_down<<<4096, 256, 0, stream>>>(pdown, xmid, out);
}